// Round 7
// baseline (360.272 us; speedup 1.0000x reference)
//
#include <hip/hip_runtime.h>

#define NEG_SLOPE 0.2f

static const int B = 4, N = 50000, R = 100000, E = 1600000;
static const int X2_CAP = 4096;     // x2 edge records (expected ~64)
static const int R2_CAP = 4096;     // r2 rows (expected ~64)
static const int N1_CAP = 4096;     // n1 nodes (expected ~1k)
static const int RS_CAP = 49152;    // row slots, r2 + r1 (expected ~28k)
static const int WIDEG = 96;        // wi-CSR slab per n1 slot (mean deg 32)
static const int RBW = 3200;        // bit-words for R rows
static const int NBW = 1600;        // bit-words for N nodes
static const int ZWORDS = RS_CAP + N1_CAP + RBW + NBW + 8;
// tails: [0]=x2tail [1]=unused [2]=n1tail [3]=slotTail [4]=r2c snapshot

// ---- scanA: wi edges with row>=N-2 -> x2list + r2 rows get slots [0,r2c) ----
__global__ void scanA(const int4* __restrict__ wi_rows4, const int4* __restrict__ wi_cols4,
                      const float4* __restrict__ wi_val4,
                      unsigned* __restrict__ bitsRS, int* __restrict__ rslot,
                      int2* __restrict__ x2list, int* __restrict__ tails, int e4) {
    int i = blockIdx.x * blockDim.x + threadIdx.x;
    if (i >= e4) return;
    int4 r = wi_rows4[i];
    int rr[4] = {r.x, r.y, r.z, r.w};
    bool any = false;
#pragma unroll
    for (int j = 0; j < 4; ++j) any = any || (rr[j] >= N - 2);
    if (!any) return;
    int4 c = wi_cols4[i];
    float4 v = wi_val4[i];
    int cc[4] = {c.x, c.y, c.z, c.w};
    float vv[4] = {v.x, v.y, v.z, v.w};
#pragma unroll
    for (int j = 0; j < 4; ++j) {
        if (rr[j] >= N - 2) {
            int col = cc[j];
            unsigned m = 1u << (col & 31);
            unsigned old = atomicOr(&bitsRS[col >> 5], m);
            if (!(old & m)) {
                int s = atomicAdd(&tails[3], 1);   // ~64 winners: negligible
                if (s < RS_CAP) rslot[col] = s;
            }
            int q = atomicAdd(&tails[0], 1);
            if (q < X2_CAP)
                x2list[q] = make_int2(col * 2 + (rr[j] - (N - 2)),
                                      __float_as_int(vv[j]));
        }
    }
}

// ---- scanB: w edges with row in r2 (bitsRS) -> n1 set, slot via block-agg ----
__global__ void scanB(const int4* __restrict__ w_rows4, const int4* __restrict__ w_cols4,
                      const unsigned* __restrict__ bitsRS, unsigned* __restrict__ bitsN1,
                      int* __restrict__ n1slot, int* __restrict__ tails, int e4) {
    __shared__ int lcount, gbase;
    __shared__ int buf[1024];
    if (threadIdx.x == 0) {
        lcount = 0;
        if (blockIdx.x == 0) tails[4] = tails[3];   // snapshot r2c
    }
    __syncthreads();
    int lane = threadIdx.x & 63;
    int i = blockIdx.x * blockDim.x + threadIdx.x;
    int4 r = make_int4(-1, -1, -1, -1);
    if (i < e4) r = w_rows4[i];
    int rr[4] = {r.x, r.y, r.z, r.w};
    unsigned fb[4];
#pragma unroll
    for (int j = 0; j < 4; ++j)
        fb[j] = (rr[j] >= 0) ? ((bitsRS[rr[j] >> 5] >> (rr[j] & 31)) & 1u) : 0u;
    bool anyf = (fb[0] | fb[1] | fb[2] | fb[3]) != 0u;
    int4 c = make_int4(0, 0, 0, 0);
    if (anyf) c = w_cols4[i];
    int cc[4] = {c.x, c.y, c.z, c.w};
#pragma unroll
    for (int j = 0; j < 4; ++j) {
        bool isnew = false;
        int n = 0;
        if (fb[j]) {
            n = cc[j];
            unsigned m = 1u << (n & 31);
            unsigned old = atomicOr(&bitsN1[n >> 5], m);
            isnew = (old & m) == 0u;
        }
        unsigned long long mb = __ballot(isnew);
        if (mb) {
            int leader = __ffsll(mb) - 1;
            int b0 = 0;
            if (lane == leader) b0 = atomicAdd(&lcount, __popcll(mb));
            b0 = __shfl(b0, leader);
            if (isnew) {
                int p = b0 + __popcll(mb & ((1ull << lane) - 1));
                if (p < 1024) buf[p] = n;
            }
        }
    }
    __syncthreads();
    int lc = lcount; if (lc > 1024) lc = 1024;
    if (threadIdx.x == 0 && lc > 0) gbase = atomicAdd(&tails[2], lc);
    __syncthreads();
    for (int t = threadIdx.x; t < lc; t += blockDim.x) {
        int slot = gbase + t;
        if (slot < N1_CAP) n1slot[buf[t]] = slot;
    }
}

// ---- scanC: wi edges with node-row in n1 -> wi-place + r1 slots (block-agg) ----
__global__ void scanC(const int4* __restrict__ wi_rows4, const int4* __restrict__ wi_cols4,
                      const float4* __restrict__ wi_val4, const float* __restrict__ diag1,
                      const unsigned* __restrict__ bitsN1, const int* __restrict__ n1slot,
                      unsigned* __restrict__ bitsRS, int* __restrict__ rslot,
                      int* __restrict__ wi_cntC, int2* __restrict__ wi_pairs,
                      int* __restrict__ tails, int e4) {
    __shared__ int lcount, gbase;
    __shared__ int buf[1024];
    if (threadIdx.x == 0) lcount = 0;
    __syncthreads();
    int lane = threadIdx.x & 63;
    int i = blockIdx.x * blockDim.x + threadIdx.x;
    int4 r = make_int4(-1, -1, -1, -1);
    if (i < e4) r = wi_rows4[i];
    int rr[4] = {r.x, r.y, r.z, r.w};
    unsigned fb[4];
#pragma unroll
    for (int j = 0; j < 4; ++j)
        fb[j] = (rr[j] >= 0) ? ((bitsN1[rr[j] >> 5] >> (rr[j] & 31)) & 1u) : 0u;
    bool anyf = (fb[0] | fb[1] | fb[2] | fb[3]) != 0u;
    int4 c = make_int4(0, 0, 0, 0);
    float4 v = make_float4(0.f, 0.f, 0.f, 0.f);
    if (anyf) { c = wi_cols4[i]; v = wi_val4[i]; }
    int cc[4] = {c.x, c.y, c.z, c.w};
    float vv[4] = {v.x, v.y, v.z, v.w};
#pragma unroll
    for (int j = 0; j < 4; ++j) {
        bool isnew = false;
        int col = 0;
        if (fb[j]) {
            col = cc[j];
            float cf = vv[j] * diag1[col];
            int slot = n1slot[rr[j]];
            if (slot >= 0 && slot < N1_CAP) {
                int pos = atomicAdd(&wi_cntC[slot], 1);
                if (pos < WIDEG)
                    wi_pairs[(size_t)slot * WIDEG + pos] =
                        make_int2(col, __float_as_int(cf));
            }
            unsigned m = 1u << (col & 31);
            unsigned old = atomicOr(&bitsRS[col >> 5], m);
            isnew = (old & m) == 0u;
        }
        unsigned long long mb = __ballot(isnew);
        if (mb) {
            int leader = __ffsll(mb) - 1;
            int b0 = 0;
            if (lane == leader) b0 = atomicAdd(&lcount, __popcll(mb));
            b0 = __shfl(b0, leader);
            if (isnew) {
                int p = b0 + __popcll(mb & ((1ull << lane) - 1));
                if (p < 1024) buf[p] = col;
            }
        }
    }
    __syncthreads();
    int lc = lcount; if (lc > 1024) lc = 1024;
    if (threadIdx.x == 0 && lc > 0) gbase = atomicAdd(&tails[3], lc);
    __syncthreads();
    for (int t = threadIdx.x; t < lc; t += blockDim.x) {
        int s = gbase + t;
        if (s < RS_CAP) rslot[buf[t]] = s;
    }
}

// ---- countD: w edges with slotted row -> per-slot degree count (L2-hot) ----
__global__ void countD(const int4* __restrict__ w_rows4,
                       const unsigned* __restrict__ bitsRS, const int* __restrict__ rslot,
                       int* __restrict__ w_cnt, int e4) {
    int i = blockIdx.x * blockDim.x + threadIdx.x;
    if (i >= e4) return;
    int4 r = w_rows4[i];
    int rr[4] = {r.x, r.y, r.z, r.w};
    unsigned fb[4];
#pragma unroll
    for (int j = 0; j < 4; ++j) fb[j] = (bitsRS[rr[j] >> 5] >> (rr[j] & 31)) & 1u;
    if (!(fb[0] | fb[1] | fb[2] | fb[3])) return;
#pragma unroll
    for (int j = 0; j < 4; ++j) {
        if (fb[j]) {
            int s = rslot[rr[j]];
            if (s >= 0 && s < RS_CAP) atomicAdd(&w_cnt[s], 1);
        }
    }
}

// ---- prefixD: one block; rowptr/cursor = exclusive prefix over w_cnt ----
__global__ void prefixD(const int* __restrict__ w_cnt, int* __restrict__ rowptr,
                        int* __restrict__ cursor, const int* __restrict__ tails) {
    __shared__ int ssum[1024];
    int tot = tails[3]; if (tot > RS_CAP) tot = RS_CAP;
    int per = (tot + 1023) >> 10;
    int lo = threadIdx.x * per;
    int hi = lo + per; if (hi > tot) hi = tot;
    int s = 0;
    for (int i = lo; i < hi; ++i) s += w_cnt[i];
    ssum[threadIdx.x] = s;
    __syncthreads();
    for (int off = 1; off < 1024; off <<= 1) {
        int t = (threadIdx.x >= off) ? ssum[threadIdx.x - off] : 0;
        __syncthreads();
        ssum[threadIdx.x] += t;
        __syncthreads();
    }
    int run = ssum[threadIdx.x] - s;      // exclusive base for this thread's span
    for (int i = lo; i < hi; ++i) {
        rowptr[i] = run;
        cursor[i] = run;
        run += w_cnt[i];
    }
}

// ---- placeD: w edges with slotted row -> exact compact CSR (L2-resident) ----
__global__ void placeD(const int4* __restrict__ w_rows4, const int4* __restrict__ w_cols4,
                       const float4* __restrict__ w_val4,
                       const unsigned* __restrict__ bitsRS, const int* __restrict__ rslot,
                       int* __restrict__ cursor, int2* __restrict__ w_pairs, int e4) {
    int i = blockIdx.x * blockDim.x + threadIdx.x;
    if (i >= e4) return;
    int4 r = w_rows4[i];
    int rr[4] = {r.x, r.y, r.z, r.w};
    unsigned fb[4];
#pragma unroll
    for (int j = 0; j < 4; ++j) fb[j] = (bitsRS[rr[j] >> 5] >> (rr[j] & 31)) & 1u;
    if (!(fb[0] | fb[1] | fb[2] | fb[3])) return;
    int4 c = w_cols4[i];
    float4 v = w_val4[i];
    int cc[4] = {c.x, c.y, c.z, c.w};
    float vv[4] = {v.x, v.y, v.z, v.w};
    int s[4];
#pragma unroll
    for (int j = 0; j < 4; ++j) s[j] = fb[j] ? rslot[rr[j]] : RS_CAP;
#pragma unroll
    for (int j = 0; j < 4; ++j) {
        if (fb[j] && s[j] >= 0 && s[j] < RS_CAP) {
            int pos = atomicAdd(&cursor[s[j]], 1);
            w_pairs[pos] = make_int2(cc[j], __float_as_int(vv[j]));
        }
    }
}

// ---- x1mlp: per n1 slot, two-hop u = (wi.d1).(w.x); h2C = lrelu(u@W1)@W2 ----
__global__ void __launch_bounds__(256) x1mlp(
        const float* __restrict__ x, const float* __restrict__ W1,
        const float* __restrict__ W2, const int* __restrict__ tails,
        const int* __restrict__ wi_cntC, const int2* __restrict__ wi_pairs,
        const int* __restrict__ rslot, const int* __restrict__ rowptr,
        const int* __restrict__ w_cnt, const int2* __restrict__ w_pairs,
        float* __restrict__ h2C) {
    __shared__ float W1s[1024], W2s[512];
    __shared__ float uls[8][128];
    __shared__ float ufin[128], x1ls[128];
    for (int i = threadIdx.x; i < 1024; i += 256) W1s[i] = W1[i];
    for (int i = threadIdx.x; i < 512; i += 256) W2s[i] = W2[i];
    int n1c = tails[2]; if (n1c > N1_CAP) n1c = N1_CAP;
    int g = threadIdx.x >> 5, t32 = threadIdx.x & 31;
    int b = t32 >> 3, c4 = t32 & 7;
    const float4* xb = (const float4*)x + (size_t)b * N * 8 + c4;
    for (int s = blockIdx.x; s < n1c; s += gridDim.x) {
        int L = wi_cntC[s]; if (L > WIDEG) L = WIDEG;
        const int2* wip = wi_pairs + (size_t)s * WIDEG;
        float4 acc = make_float4(0.f, 0.f, 0.f, 0.f);
        for (int e = g; e < L; e += 8) {
            int2 pe = wip[e];
            int rs = rslot[pe.x];
            float coef = __int_as_float(pe.y);        // diag1 folded
            if (rs < 0 || rs >= RS_CAP) continue;
            int start = rowptr[rs];
            int Lw = w_cnt[rs];
            const int2* pr = w_pairs + start;
            float4 t = make_float4(0.f, 0.f, 0.f, 0.f);
            int i = 0;
            int L4 = Lw & ~3;
            for (; i < L4; i += 4) {
                int2 p0 = pr[i + 0];
                int2 p1 = pr[i + 1];
                int2 p2 = pr[i + 2];
                int2 p3 = pr[i + 3];
                float4 s0 = xb[(size_t)p0.x * 8];
                float4 s1 = xb[(size_t)p1.x * 8];
                float4 s2 = xb[(size_t)p2.x * 8];
                float4 s3 = xb[(size_t)p3.x * 8];
                float v0 = __int_as_float(p0.y), v1 = __int_as_float(p1.y);
                float v2 = __int_as_float(p2.y), v3 = __int_as_float(p3.y);
                t.x += v0 * s0.x + v1 * s1.x + v2 * s2.x + v3 * s3.x;
                t.y += v0 * s0.y + v1 * s1.y + v2 * s2.y + v3 * s3.y;
                t.z += v0 * s0.z + v1 * s1.z + v2 * s2.z + v3 * s3.z;
                t.w += v0 * s0.w + v1 * s1.w + v2 * s2.w + v3 * s3.w;
            }
            for (; i < Lw; ++i) {
                int2 p = pr[i];
                float4 sv = xb[(size_t)p.x * 8];
                float v = __int_as_float(p.y);
                t.x += v * sv.x; t.y += v * sv.y; t.z += v * sv.z; t.w += v * sv.w;
            }
            acc.x += coef * t.x; acc.y += coef * t.y;
            acc.z += coef * t.z; acc.w += coef * t.w;
        }
        float* up = &uls[g][b * 32 + c4 * 4];
        up[0] = acc.x; up[1] = acc.y; up[2] = acc.z; up[3] = acc.w;
        __syncthreads();
        if (threadIdx.x < 128) {
            float sum = 0.f;
#pragma unroll
            for (int gg = 0; gg < 8; ++gg) sum += uls[gg][threadIdx.x];
            ufin[threadIdx.x] = sum;
        }
        __syncthreads();
        if (threadIdx.x < 128) {
            int bb = threadIdx.x >> 5, c = threadIdx.x & 31;
            const float* ur = &ufin[bb * 32];
            float o = 0.f;
#pragma unroll
            for (int k = 0; k < 32; ++k) o += ur[k] * W1s[k * 32 + c];
            x1ls[threadIdx.x] = o > 0.f ? o : NEG_SLOPE * o;
        }
        __syncthreads();
        if (threadIdx.x < 64) {
            int bb = threadIdx.x >> 4, c = threadIdx.x & 15;
            const float* xr = &x1ls[bb * 32];
            float o = 0.f;
#pragma unroll
            for (int k = 0; k < 32; ++k) o += xr[k] * W2s[k * 16 + c];
            h2C[(size_t)s * 64 + bb * 16 + c] = o;
        }
        __syncthreads();
    }
}

// ---- t2 gather (r2 slots, CSR) + x2 accumulation + heads, ONE block ----
__global__ void t2x2heads(const float* __restrict__ h2C,
                          const int* __restrict__ rowptr, const int* __restrict__ w_cnt,
                          const int2* __restrict__ w_pairs,
                          const int* __restrict__ n1slot, const int* __restrict__ rslot,
                          const int* __restrict__ tails, float* __restrict__ t2C,
                          const int2* __restrict__ x2list,
                          const float* __restrict__ diag2,
                          const float* __restrict__ rw1, const float* __restrict__ rb1,
                          const float* __restrict__ rw2, const float* __restrict__ rb2,
                          float* __restrict__ out) {
    // phase 1: t2 over r2 slots [0, r2c), 16 float4-lanes per slot
    int r2c = tails[4]; if (r2c > R2_CAP) r2c = R2_CAP;
    for (int idx = threadIdx.x; idx < r2c * 16; idx += blockDim.x) {
        int s = idx >> 4;
        int rem = idx & 15;
        int c4 = rem & 3;
        int b = rem >> 2;
        int L = w_cnt[s];
        const int2* pr = w_pairs + rowptr[s];
        const float4* sb = (const float4*)h2C + b * 4 + c4;
        float4 acc = make_float4(0.f, 0.f, 0.f, 0.f);
        for (int i = 0; i < L; ++i) {
            int2 p = pr[i];
            int hs = n1slot[p.x];               // col is n1 by construction
            float v = __int_as_float(p.y);
            if (hs >= 0 && hs < N1_CAP) {
                float4 sv = sb[(size_t)hs * 16];
                acc.x += v * sv.x; acc.y += v * sv.y; acc.z += v * sv.z; acc.w += v * sv.w;
            }
        }
        ((float4*)t2C)[(size_t)s * 16 + b * 4 + c4] = acc;
    }
    __syncthreads();

    // phase 2: x2 accumulation, edge-parallel across 16 groups of 64 lanes
    int cnt = tails[0]; if (cnt > X2_CAP) cnt = X2_CAP;
    int g = threadIdx.x >> 6, l = threadIdx.x & 63;
    int b = l >> 4, c = l & 15;
    float a0 = 0.f, a1 = 0.f;
    for (int i = g; i < cnt; i += 16) {
        int2 rec = x2list[i];
        int col = rec.x >> 1;
        int s = rslot[col];
        float coef = __int_as_float(rec.y) * diag2[col];
        float v = (s >= 0 && s < R2_CAP) ? t2C[(size_t)s * 64 + b * 16 + c] * coef : 0.f;
        if (rec.x & 1) a1 += v; else a0 += v;
    }
    __shared__ float red0[16][64], red1[16][64], xs[2][64];
    red0[g][l] = a0; red1[g][l] = a1;
    __syncthreads();
    if (threadIdx.x < 64) {
        float s0 = 0.f, s1 = 0.f;
#pragma unroll
        for (int gg = 0; gg < 16; ++gg) { s0 += red0[gg][threadIdx.x]; s1 += red1[gg][threadIdx.x]; }
        xs[0][threadIdx.x] = s0; xs[1][threadIdx.x] = s1;
    }
    __syncthreads();
    if (threadIdx.x < 8) {
        int bb = threadIdx.x >> 1, which = threadIdx.x & 1;
        const float* w = which ? rw2 : rw1;
        float acc = which ? rb2[0] : rb1[0];
        for (int k = 0; k < 16; ++k) {
            float xv = xs[which][bb * 16 + k];
            xv = xv > 0.f ? xv : NEG_SLOPE * xv;
            acc += xv * w[k];
        }
        out[bb * 2 + which] = acc;
    }
}

extern "C" void kernel_launch(void* const* d_in, const int* in_sizes, int n_in,
                              void* d_out, int out_size, void* d_ws, size_t ws_size,
                              hipStream_t stream) {
    const int*   w_rows  = (const int*)d_in[0];
    const int*   w_cols  = ((const int*)d_in[0]) + E;
    const float* w_val   = (const float*)d_in[1];
    const int*   wi_rows = (const int*)d_in[2];
    const int*   wi_cols = ((const int*)d_in[2]) + E;
    const float* wi_val  = (const float*)d_in[3];
    const float* x       = (const float*)d_in[4];
    const float* W1      = (const float*)d_in[5];
    const float* diag1   = (const float*)d_in[6];
    const float* W2      = (const float*)d_in[7];
    const float* diag2   = (const float*)d_in[8];
    const float* rw1     = (const float*)d_in[9];
    const float* rb1     = (const float*)d_in[10];
    const float* rw2     = (const float*)d_in[11];
    const float* rb2     = (const float*)d_in[12];
    float* out = (float*)d_out;

    // ---------------- workspace layout (~20 MB) ----------------
    float* h2C = (float*)d_ws;                       // [N1_CAP][64]  (1 MB)
    float* t2C = h2C + (size_t)N1_CAP * 64;          // [R2_CAP][64]  (1 MB)
    int* ip = (int*)(t2C + (size_t)R2_CAP * 64);
    // zeroed block (contiguous, ZWORDS words):
    int* w_cnt   = ip; ip += RS_CAP;
    int* wi_cntC = ip; ip += N1_CAP;
    unsigned* bitsRS = (unsigned*)ip; ip += RBW;
    unsigned* bitsN1 = (unsigned*)ip; ip += NBW;
    int* tails = ip; ip += 8;
    // un-zeroed:
    int* rowptr = ip; ip += RS_CAP + 8;
    int* cursor = ip; ip += RS_CAP;
    int* rslot  = ip; ip += R;
    int* n1slot = ip; ip += N;
    int2* x2list = (int2*)ip; ip += 2 * X2_CAP;
    int2* w_pairs  = (int2*)ip; ip += 2 * (size_t)E;                // 12.8 MB (exact CSR)
    int2* wi_pairs = (int2*)ip; ip += 2 * (size_t)N1_CAP * WIDEG;   // 3.1 MB

    const int e4 = E / 4;
    const int blk = 256;
    const int scanGrid = (e4 + blk - 1) / blk;

    (void)hipMemsetAsync(w_cnt, 0, (size_t)ZWORDS * sizeof(int), stream);

    scanA<<<scanGrid, blk, 0, stream>>>((const int4*)wi_rows, (const int4*)wi_cols,
                                        (const float4*)wi_val, bitsRS, rslot,
                                        x2list, tails, e4);
    scanB<<<scanGrid, blk, 0, stream>>>((const int4*)w_rows, (const int4*)w_cols,
                                        bitsRS, bitsN1, n1slot, tails, e4);
    scanC<<<scanGrid, blk, 0, stream>>>((const int4*)wi_rows, (const int4*)wi_cols,
                                        (const float4*)wi_val, diag1, bitsN1, n1slot,
                                        bitsRS, rslot, wi_cntC, wi_pairs, tails, e4);
    countD<<<scanGrid, blk, 0, stream>>>((const int4*)w_rows, bitsRS, rslot, w_cnt, e4);
    prefixD<<<1, 1024, 0, stream>>>(w_cnt, rowptr, cursor, tails);
    placeD<<<scanGrid, blk, 0, stream>>>((const int4*)w_rows, (const int4*)w_cols,
                                         (const float4*)w_val, bitsRS, rslot,
                                         cursor, w_pairs, e4);
    x1mlp<<<1024, blk, 0, stream>>>(x, W1, W2, tails, wi_cntC, wi_pairs,
                                    rslot, rowptr, w_cnt, w_pairs, h2C);
    t2x2heads<<<1, 1024, 0, stream>>>(h2C, rowptr, w_cnt, w_pairs, n1slot, rslot,
                                      tails, t2C, x2list, diag2,
                                      rw1, rb1, rw2, rb2, out);
}